// Round 1
// baseline (1327.801 us; speedup 1.0000x reference)
//
#include <hip/hip_runtime.h>
#include <hip/hip_bf16.h>

// Problem constants
#define BATCH   2048
#define HW      81          // 9x9
#define CIN     39
#define NPIX    (BATCH*HW)  // 165888

// ws layout (float offsets)
#define WS_H1     0              // 10,616,832 floats  (B,64,81)
#define WS_MASK   10616832       // 1,492,992 floats   (B,9,81)
#define WS_W1T    12109824       // 23,040  [tap][c4(10)][o(64)][4]
#define WS_WCT    12132864       // 18,432  [tap][c4(16)][oc(32)][4]
#define WS_WDT    12151296       // 36,864  [k][c][o]
#define WS_STATS  12188160       // 512: sum1,sq1,sum2,sq2,scale1,shift1,scale2,shift2 (64 each)

#define OUT_OFF_BASE 1
#define OUT_H_BASE   (1 + BATCH*18*81)   // 2985985

// ---------------- weight prep: transpose into lane-coalesced layouts ----------
__global__ void prep_weights(const float* __restrict__ w1, const float* __restrict__ wo,
                             const float* __restrict__ wm, const float* __restrict__ wd,
                             float* __restrict__ ws) {
    int idx = blockIdx.x * 256 + threadIdx.x;
    float* w1t = ws + WS_W1T;
    float* wct = ws + WS_WCT;
    float* wdt = ws + WS_WDT;
    if (idx < 23040) {
        int cc = idx & 3; int r = idx >> 2; int o = r & 63; r >>= 6;
        int c4 = r % 10; int tap = r / 10;
        int c = c4 * 4 + cc;
        w1t[idx] = (c < CIN) ? w1[(o * CIN + c) * 9 + tap] : 0.f;
        return;
    }
    int j = idx - 23040;
    if (j >= 0 && j < 18432) {
        int cc = j & 3; int r = j >> 2; int oc = r & 31; r >>= 5;
        int c4 = r & 15; int tap = r >> 4;
        int c = c4 * 4 + cc;
        float v = 0.f;
        if (oc < 18)      v = wo[(oc * 64 + c) * 9 + tap];
        else if (oc < 27) v = wm[((oc - 18) * 64 + c) * 9 + tap];
        wct[j] = v;
        return;
    }
    int m = idx - 23040 - 18432;
    if (m >= 0 && m < 36864) {
        int o = m & 63; int r = m >> 6; int c = r & 63; int k = r >> 6;
        wdt[m] = wd[(o * 64 + c) * 9 + k];
    }
}

// ---------------- conv1 (39->64) + ReLU + BN1 stats ---------------------------
__global__ __launch_bounds__(256) void conv1_bn_stats(
        const float* __restrict__ xg, const float* __restrict__ b1,
        const float* __restrict__ w1t, float* __restrict__ h1,
        float* __restrict__ sum1, float* __restrict__ sq1) {
    __shared__ float xs[5040];         // 126 rows * 40 (c padded), zero padded
    __shared__ float rs[64], rq[64];
    int b = blockIdx.x, t = threadIdx.x;
    for (int i = t; i < 5040; i += 256) xs[i] = 0.f;
    if (t < 64) { rs[t] = 0.f; rq[t] = 0.f; }
    __syncthreads();
    const float* xb = xg + (size_t)b * (HW * CIN);
    for (int i = t; i < HW * CIN; i += 256) {
        int y = i / (9 * CIN), r = i - y * (9 * CIN);
        int xx = r / CIN, c = r - xx * CIN;
        xs[((y + 1) * 11 + (xx + 1)) * 40 + c] = xb[i];
    }
    __syncthreads();
    int o = t & 63, g = t >> 6;
    float acc[21];
#pragma unroll
    for (int j = 0; j < 21; ++j) acc[j] = 0.f;
    int pb[21];
#pragma unroll
    for (int j = 0; j < 21; ++j) { int p = g + 4 * j; int y = p / 9, xx = p - y * 9; pb[j] = y * 11 + xx; }
    const float4* w4 = (const float4*)w1t;
    for (int tap = 0; tap < 9; ++tap) {
        int off = (tap / 3) * 11 + (tap % 3);
        for (int c4 = 0; c4 < 10; ++c4) {
            float4 w = w4[(tap * 10 + c4) * 64 + o];
#pragma unroll
            for (int j = 0; j < 21; ++j) {
                const float4 v = *(const float4*)&xs[(pb[j] + off) * 40 + c4 * 4];
                acc[j] += w.x * v.x + w.y * v.y + w.z * v.z + w.w * v.w;
            }
        }
    }
    float bias = b1[o];
    float ts = 0.f, tq = 0.f;
    float* h1b = h1 + (size_t)b * 5184;
#pragma unroll
    for (int j = 0; j < 21; ++j) {
        int p = g + 4 * j;
        if (p < 81) {
            float v = fmaxf(acc[j] + bias, 0.f);
            h1b[o * 81 + p] = v;
            ts += v; tq += v * v;
        }
    }
    atomicAdd(&rs[o], ts); atomicAdd(&rq[o], tq);
    __syncthreads();
    if (t < 64) { atomicAdd(&sum1[t], rs[t]); atomicAdd(&sq1[t], rq[t]); }
}

// ---------------- BN finalize -------------------------------------------------
__global__ void bn_finalize(const float* __restrict__ sums, const float* __restrict__ sqs,
                            const float* __restrict__ gamma, const float* __restrict__ beta,
                            float* __restrict__ scale, float* __restrict__ shift) {
    int t = threadIdx.x;   // 64
    float m = sums[t] / (float)NPIX;
    float v = sqs[t] / (float)NPIX - m * m;
    float sc = gamma[t] * (1.f / sqrtf(v + 1e-5f));
    scale[t] = sc;
    shift[t] = beta[t] - m * sc;
}

// ---------------- BN apply (elementwise, layout (b,c,81)) ---------------------
__global__ void bn_apply(float* __restrict__ data, const float* __restrict__ scale,
                         const float* __restrict__ shift, int n, int writeProb,
                         float* __restrict__ dout) {
    int i = blockIdx.x * blockDim.x + threadIdx.x;
    if (writeProb && i == 0) dout[0] = 0.5f;
    for (; i < n; i += gridDim.x * blockDim.x) {
        int c = (i / 81) & 63;
        data[i] = data[i] * scale[c] + shift[c];
    }
}

// ---------------- offset(18) + mask(9, sigmoid) conv --------------------------
__global__ __launch_bounds__(256) void conv_offmask(
        const float* __restrict__ h1, const float* __restrict__ wct,
        const float* __restrict__ bo, const float* __restrict__ bm,
        float* __restrict__ dout, float* __restrict__ maskbuf) {
    __shared__ float hs[8840];   // 130 rows * 68 (c stride 68), zero padded
    int b = blockIdx.x, t = threadIdx.x;
    for (int i = t; i < 8840; i += 256) hs[i] = 0.f;
    __syncthreads();
    const float* hb = h1 + (size_t)b * 5184;
    for (int i = t; i < 5184; i += 256) {
        int c = i / 81, p = i - c * 81;
        int y = p / 9, xx = p - y * 9;
        hs[((y + 1) * 11 + xx + 1) * 68 + c] = hb[i];
    }
    __syncthreads();
    int oc = t & 31, g = t >> 5;
    float acc[11];
#pragma unroll
    for (int j = 0; j < 11; ++j) acc[j] = 0.f;
    int pb[11];
#pragma unroll
    for (int j = 0; j < 11; ++j) { int p = g + 8 * j; int y = p / 9, xx = p - y * 9; pb[j] = y * 11 + xx; }
    const float4* w4 = (const float4*)wct;
    for (int tap = 0; tap < 9; ++tap) {
        int off = (tap / 3) * 11 + (tap % 3);
        for (int c4 = 0; c4 < 16; ++c4) {
            float4 w = w4[(tap * 16 + c4) * 32 + oc];
#pragma unroll
            for (int j = 0; j < 11; ++j) {
                const float4 v = *(const float4*)&hs[(pb[j] + off) * 68 + c4 * 4];
                acc[j] += w.x * v.x + w.y * v.y + w.z * v.z + w.w * v.w;
            }
        }
    }
    if (oc < 18) {
        float bias = bo[oc];
        float* ob = dout + OUT_OFF_BASE + (size_t)b * 1458 + oc * 81;
#pragma unroll
        for (int j = 0; j < 11; ++j) { int p = g + 8 * j; if (p < 81) ob[p] = acc[j] + bias; }
    } else if (oc < 27) {
        float bias = bm[oc - 18];
        float* mb = maskbuf + (size_t)b * 729 + (oc - 18) * 81;
#pragma unroll
        for (int j = 0; j < 11; ++j) {
            int p = g + 8 * j;
            if (p < 81) { float v = acc[j] + bias; mb[p] = 1.f / (1.f + expf(-v)); }
        }
    }
}

// ---------------- deformable conv + BN2 stats ---------------------------------
__global__ __launch_bounds__(256) void deform_conv(
        const float* __restrict__ h1, const float* __restrict__ wdt,
        const float* __restrict__ maskbuf, const float* __restrict__ bd,
        float* __restrict__ dout, float* __restrict__ sum2, float* __restrict__ sq2) {
    __shared__ float hs[5184];     // [c][81]
    __shared__ float vs[5184];     // [c][81]
    __shared__ float wsh[4096];    // [c][o]
    __shared__ float om[2187];     // offsets (18*81) + mask (9*81)
    __shared__ float rs[64], rq[64];
    int b = blockIdx.x, t = threadIdx.x;
    const float* hb = h1 + (size_t)b * 5184;
    for (int i = t; i < 5184; i += 256) hs[i] = hb[i];
    const float* ob = dout + OUT_OFF_BASE + (size_t)b * 1458;
    for (int i = t; i < 1458; i += 256) om[i] = ob[i];
    const float* mb = maskbuf + (size_t)b * 729;
    for (int i = t; i < 729; i += 256) om[1458 + i] = mb[i];
    if (t < 64) { rs[t] = 0.f; rq[t] = 0.f; }
    int to = t & 7, tp = t >> 3;
    int o0 = to * 8, p0 = tp * 3;
    bool active = tp < 27;
    float acc[8][3];
#pragma unroll
    for (int i = 0; i < 8; ++i)
#pragma unroll
        for (int j = 0; j < 3; ++j) acc[i][j] = 0.f;

    for (int k = 0; k < 9; ++k) {
        __syncthreads();   // protects vs/wsh from previous phase-2 readers; also covers initial loads
        for (int i = t; i < 4096; i += 256) wsh[i] = wdt[k * 4096 + i];
        int ky = k / 3 - 1, kx = k % 3 - 1;
        for (int i = t; i < 5184; i += 256) {
            int c = i / 81, p = i - c * 81;
            int y = p / 9, xx = p - y * 9;
            float dy = om[(2 * k) * 81 + p], dx = om[(2 * k + 1) * 81 + p];
            float m  = om[1458 + k * 81 + p];
            float py = dy + (float)(y + ky);
            float px = dx + (float)(xx + kx);
            float fy = floorf(py), fx = floorf(px);
            float ly = py - fy, lx = px - fx;
            int y0 = (int)fy, x0 = (int)fx;
            int y1 = y0 + 1, x1 = x0 + 1;
            float w00 = (1.f - ly) * (1.f - lx);
            float w01 = (1.f - ly) * lx;
            float w10 = ly * (1.f - lx);
            float w11 = ly * lx;
            bool vy0 = (y0 >= 0) & (y0 < 9), vy1 = (y1 >= 0) & (y1 < 9);
            bool vx0 = (x0 >= 0) & (x0 < 9), vx1 = (x1 >= 0) & (x1 < 9);
            int yc0 = min(max(y0, 0), 8), yc1 = min(max(y1, 0), 8);
            int xc0 = min(max(x0, 0), 8), xc1 = min(max(x1, 0), 8);
            const float* hc = &hs[c * 81];
            float s = 0.f;
            s += (vy0 && vx0) ? w00 * hc[yc0 * 9 + xc0] : 0.f;
            s += (vy0 && vx1) ? w01 * hc[yc0 * 9 + xc1] : 0.f;
            s += (vy1 && vx0) ? w10 * hc[yc1 * 9 + xc0] : 0.f;
            s += (vy1 && vx1) ? w11 * hc[yc1 * 9 + xc1] : 0.f;
            vs[i] = m * s;
        }
        __syncthreads();
        if (active) {
            for (int c = 0; c < 64; ++c) {
                float wv[8];
                *(float4*)&wv[0] = *(const float4*)&wsh[c * 64 + o0];
                *(float4*)&wv[4] = *(const float4*)&wsh[c * 64 + o0 + 4];
                float v0 = vs[c * 81 + p0];
                float v1 = vs[c * 81 + p0 + 1];
                float v2 = vs[c * 81 + p0 + 2];
#pragma unroll
                for (int i = 0; i < 8; ++i) {
                    acc[i][0] += wv[i] * v0;
                    acc[i][1] += wv[i] * v1;
                    acc[i][2] += wv[i] * v2;
                }
            }
        }
    }
    if (active) {
        float* outb = dout + OUT_H_BASE + (size_t)b * 5184;
#pragma unroll
        for (int i = 0; i < 8; ++i) {
            float bias = bd[o0 + i];
            float ss = 0.f, qq = 0.f;
#pragma unroll
            for (int j = 0; j < 3; ++j) {
                float v = acc[i][j] + bias;
                outb[(o0 + i) * 81 + p0 + j] = v;
                ss += v; qq += v * v;
            }
            atomicAdd(&rs[o0 + i], ss); atomicAdd(&rq[o0 + i], qq);
        }
    }
    __syncthreads();
    if (t < 64) { atomicAdd(&sum2[t], rs[t]); atomicAdd(&sq2[t], rq[t]); }
}

// ---------------- launch -------------------------------------------------------
extern "C" void kernel_launch(void* const* d_in, const int* in_sizes, int n_in,
                              void* d_out, int out_size, void* d_ws, size_t ws_size,
                              hipStream_t stream) {
    const float* x   = (const float*)d_in[0];
    const float* w1  = (const float*)d_in[1];
    const float* b1  = (const float*)d_in[2];
    const float* g1  = (const float*)d_in[3];
    const float* be1 = (const float*)d_in[4];
    const float* wo  = (const float*)d_in[5];
    const float* bo  = (const float*)d_in[6];
    const float* wm  = (const float*)d_in[7];
    const float* bm  = (const float*)d_in[8];
    const float* wd  = (const float*)d_in[9];
    const float* bd  = (const float*)d_in[10];
    const float* g2  = (const float*)d_in[11];
    const float* be2 = (const float*)d_in[12];
    float* dout = (float*)d_out;
    float* ws   = (float*)d_ws;

    float* h1    = ws + WS_H1;
    float* maskb = ws + WS_MASK;
    float* w1t   = ws + WS_W1T;
    float* wct   = ws + WS_WCT;
    float* wdt   = ws + WS_WDT;
    float* stats = ws + WS_STATS;
    float* sum1 = stats, *sq1 = stats + 64, *sum2 = stats + 128, *sq2 = stats + 192;
    float* scale1 = stats + 256, *shift1 = stats + 320, *scale2 = stats + 384, *shift2 = stats + 448;

    // zero the BN accumulators (ws is NOT re-poisoned between replays)
    hipMemsetAsync(stats, 0, 256 * sizeof(float), stream);

    prep_weights<<<306, 256, 0, stream>>>(w1, wo, wm, wd, ws);
    conv1_bn_stats<<<BATCH, 256, 0, stream>>>(x, b1, w1t, h1, sum1, sq1);
    bn_finalize<<<1, 64, 0, stream>>>(sum1, sq1, g1, be1, scale1, shift1);
    bn_apply<<<2048, 256, 0, stream>>>(h1, scale1, shift1, BATCH * 5184, 0, dout);
    conv_offmask<<<BATCH, 256, 0, stream>>>(h1, wct, bo, bm, dout, maskb);
    deform_conv<<<BATCH, 256, 0, stream>>>(h1, wdt, maskb, bd, dout, sum2, sq2);
    bn_finalize<<<1, 64, 0, stream>>>(sum2, sq2, g2, be2, scale2, shift2);
    bn_apply<<<2048, 256, 0, stream>>>(dout + OUT_H_BASE, scale2, shift2, BATCH * 5184, 1, dout);
}

// Round 2
// 983.323 us; speedup vs baseline: 1.3503x; 1.3503x over previous
//
#include <hip/hip_runtime.h>
#include <hip/hip_bf16.h>

// Problem constants
#define BATCH   2048
#define HW      81          // 9x9
#define CIN     39
#define NPIX    (BATCH*HW)  // 165888

// ws layout (float offsets)
#define WS_H1     0              // 10,616,832 floats  (B,64,81)
#define WS_MASK   10616832       // 1,492,992 floats   (B,9,81)
#define WS_W1T    12109824       // 23,040  [tap][c4(10)][o(64)][4]
#define WS_WCT    12132864       // 18,432  [tap][c4(16)][oc(32)][4]
#define WS_WDT    12151296       // 36,864 ushort bf16 [k][o][c]  (18,432 floats of space)
#define WS_STATS  12188160       // 512: sum1,sq1,sum2,sq2,scale1,shift1,scale2,shift2 (64 each)

#define OUT_OFF_BASE 1
#define OUT_H_BASE   (1 + BATCH*18*81)   // 2985985

typedef __attribute__((ext_vector_type(8))) short bfrag8;
typedef __attribute__((ext_vector_type(4))) float floatx4;

__device__ __forceinline__ unsigned short f2bf(float f) {
    unsigned u = __builtin_bit_cast(unsigned, f);
    u += 0x7FFFu + ((u >> 16) & 1u);       // round-to-nearest-even
    return (unsigned short)(u >> 16);
}
__device__ __forceinline__ float bfhi2f(unsigned hi16) {   // hi16 already in bits 31..16
    return __builtin_bit_cast(float, hi16);
}

// ---------------- weight prep: transpose into lane-coalesced layouts ----------
__global__ void prep_weights(const float* __restrict__ w1, const float* __restrict__ wo,
                             const float* __restrict__ wm, const float* __restrict__ wd,
                             float* __restrict__ ws) {
    int idx = blockIdx.x * 256 + threadIdx.x;
    float* w1t = ws + WS_W1T;
    float* wct = ws + WS_WCT;
    unsigned short* wdt16 = (unsigned short*)(ws + WS_WDT);
    if (idx < 23040) {
        int cc = idx & 3; int r = idx >> 2; int o = r & 63; r >>= 6;
        int c4 = r % 10; int tap = r / 10;
        int c = c4 * 4 + cc;
        w1t[idx] = (c < CIN) ? w1[(o * CIN + c) * 9 + tap] : 0.f;
        return;
    }
    int j = idx - 23040;
    if (j >= 0 && j < 18432) {
        int cc = j & 3; int r = j >> 2; int oc = r & 31; r >>= 5;
        int c4 = r & 15; int tap = r >> 4;
        int c = c4 * 4 + cc;
        float v = 0.f;
        if (oc < 18)      v = wo[(oc * 64 + c) * 9 + tap];
        else if (oc < 27) v = wm[((oc - 18) * 64 + c) * 9 + tap];
        wct[j] = v;
        return;
    }
    int m = idx - 23040 - 18432;
    if (m >= 0 && m < 36864) {
        int c = m & 63; int r = m >> 6; int o = r & 63; int k = r >> 6;
        wdt16[m] = f2bf(wd[(o * 64 + c) * 9 + k]);   // [k][o][c] bf16
    }
}

// ---------------- conv1 (39->64) + ReLU + BN1 stats ---------------------------
__global__ __launch_bounds__(256) void conv1_bn_stats(
        const float* __restrict__ xg, const float* __restrict__ b1,
        const float* __restrict__ w1t, float* __restrict__ h1,
        float* __restrict__ sum1, float* __restrict__ sq1) {
    __shared__ float xs[5040];         // 126 rows * 40 (c padded), zero padded
    __shared__ float rs[64], rq[64];
    int b = blockIdx.x, t = threadIdx.x;
    for (int i = t; i < 5040; i += 256) xs[i] = 0.f;
    if (t < 64) { rs[t] = 0.f; rq[t] = 0.f; }
    __syncthreads();
    const float* xb = xg + (size_t)b * (HW * CIN);
    for (int i = t; i < HW * CIN; i += 256) {
        int y = i / (9 * CIN), r = i - y * (9 * CIN);
        int xx = r / CIN, c = r - xx * CIN;
        xs[((y + 1) * 11 + (xx + 1)) * 40 + c] = xb[i];
    }
    __syncthreads();
    int o = t & 63, g = t >> 6;
    float acc[21];
#pragma unroll
    for (int j = 0; j < 21; ++j) acc[j] = 0.f;
    int pb[21];
#pragma unroll
    for (int j = 0; j < 21; ++j) { int p = g + 4 * j; int y = p / 9, xx = p - y * 9; pb[j] = y * 11 + xx; }
    const float4* w4 = (const float4*)w1t;
    for (int tap = 0; tap < 9; ++tap) {
        int off = (tap / 3) * 11 + (tap % 3);
        for (int c4 = 0; c4 < 10; ++c4) {
            float4 w = w4[(tap * 10 + c4) * 64 + o];
#pragma unroll
            for (int j = 0; j < 21; ++j) {
                const float4 v = *(const float4*)&xs[(pb[j] + off) * 40 + c4 * 4];
                acc[j] += w.x * v.x + w.y * v.y + w.z * v.z + w.w * v.w;
            }
        }
    }
    float bias = b1[o];
    float ts = 0.f, tq = 0.f;
    float* h1b = h1 + (size_t)b * 5184;
#pragma unroll
    for (int j = 0; j < 21; ++j) {
        int p = g + 4 * j;
        if (p < 81) {
            float v = fmaxf(acc[j] + bias, 0.f);
            h1b[o * 81 + p] = v;
            ts += v; tq += v * v;
        }
    }
    atomicAdd(&rs[o], ts); atomicAdd(&rq[o], tq);
    __syncthreads();
    if (t < 64) { atomicAdd(&sum1[t], rs[t]); atomicAdd(&sq1[t], rq[t]); }
}

// ---------------- BN finalize -------------------------------------------------
__global__ void bn_finalize(const float* __restrict__ sums, const float* __restrict__ sqs,
                            const float* __restrict__ gamma, const float* __restrict__ beta,
                            float* __restrict__ scale, float* __restrict__ shift) {
    int t = threadIdx.x;   // 64
    float m = sums[t] / (float)NPIX;
    float v = sqs[t] / (float)NPIX - m * m;
    float sc = gamma[t] * (1.f / sqrtf(v + 1e-5f));
    scale[t] = sc;
    shift[t] = beta[t] - m * sc;
}

// ---------------- BN apply (elementwise, layout (b,c,81)) ---------------------
__global__ void bn_apply(float* __restrict__ data, const float* __restrict__ scale,
                         const float* __restrict__ shift, int n, int writeProb,
                         float* __restrict__ dout) {
    int i = blockIdx.x * blockDim.x + threadIdx.x;
    if (writeProb && i == 0) dout[0] = 0.5f;
    for (; i < n; i += gridDim.x * blockDim.x) {
        int c = (i / 81) & 63;
        data[i] = data[i] * scale[c] + shift[c];
    }
}

// ---------------- offset(18) + mask(9, sigmoid) conv --------------------------
__global__ __launch_bounds__(256) void conv_offmask(
        const float* __restrict__ h1, const float* __restrict__ wct,
        const float* __restrict__ bo, const float* __restrict__ bm,
        float* __restrict__ dout, float* __restrict__ maskbuf) {
    __shared__ float hs[8840];   // 130 rows * 68 (c stride 68), zero padded
    int b = blockIdx.x, t = threadIdx.x;
    for (int i = t; i < 8840; i += 256) hs[i] = 0.f;
    __syncthreads();
    const float* hb = h1 + (size_t)b * 5184;
    for (int i = t; i < 5184; i += 256) {
        int c = i / 81, p = i - c * 81;
        int y = p / 9, xx = p - y * 9;
        hs[((y + 1) * 11 + xx + 1) * 68 + c] = hb[i];
    }
    __syncthreads();
    int oc = t & 31, g = t >> 5;
    float acc[11];
#pragma unroll
    for (int j = 0; j < 11; ++j) acc[j] = 0.f;
    int pb[11];
#pragma unroll
    for (int j = 0; j < 11; ++j) { int p = g + 8 * j; int y = p / 9, xx = p - y * 9; pb[j] = y * 11 + xx; }
    const float4* w4 = (const float4*)wct;
    for (int tap = 0; tap < 9; ++tap) {
        int off = (tap / 3) * 11 + (tap % 3);
        for (int c4 = 0; c4 < 16; ++c4) {
            float4 w = w4[(tap * 16 + c4) * 32 + oc];
#pragma unroll
            for (int j = 0; j < 11; ++j) {
                const float4 v = *(const float4*)&hs[(pb[j] + off) * 68 + c4 * 4];
                acc[j] += w.x * v.x + w.y * v.y + w.z * v.z + w.w * v.w;
            }
        }
    }
    if (oc < 18) {
        float bias = bo[oc];
        float* ob = dout + OUT_OFF_BASE + (size_t)b * 1458 + oc * 81;
#pragma unroll
        for (int j = 0; j < 11; ++j) { int p = g + 8 * j; if (p < 81) ob[p] = acc[j] + bias; }
    } else if (oc < 27) {
        float bias = bm[oc - 18];
        float* mb = maskbuf + (size_t)b * 729 + (oc - 18) * 81;
#pragma unroll
        for (int j = 0; j < 11; ++j) {
            int p = g + 8 * j;
            if (p < 81) { float v = acc[j] + bias; mb[p] = 1.f / (1.f + expf(-v)); }
        }
    }
}

// ---------------- deformable conv (MFMA) + BN2 stats --------------------------
// Per image: out[64 o][81 p] = sum over tap k of W_k[64 o][64 c] * V_k[64 c][81 p]
// V_k[c][p] = mask[k][p] * bilinear(h[c], offset(k,p)).
// bf16 MFMA 16x16x32; A/B fragments use a consistent bijective k-map (b128 frag
// loads), which is correct regardless of HW k-ordering; C/D layout per m89.
#define VSTR 72
__global__ __launch_bounds__(256) void deform_mfma(
        const float* __restrict__ h1, const unsigned short* __restrict__ wdt16,
        const float* __restrict__ maskbuf, const float* __restrict__ bd,
        float* __restrict__ dout, float* __restrict__ sum2, float* __restrict__ sq2) {
    __shared__ float hsh[5184];                 // [c][81] fp32
    __shared__ uint2 bwt[729];                  // [k][p] 4x bf16 weights (pre-masked)
    __shared__ unsigned bix[729];               // [k][p] 4x u8 corner indices
    __shared__ short wk[2][64 * VSTR];          // [o][c] bf16, double buffered
    __shared__ short vt[2][96 * VSTR];          // [p][c] bf16, double buffered
    __shared__ float bdsh[64];

    int b = blockIdx.x, t = threadIdx.x;

    // ---- stage h (fp32), bias
    const float* hb = h1 + (size_t)b * 5184;
    for (int i = t; i < 1296; i += 256) ((float4*)hsh)[i] = ((const float4*)hb)[i];
    if (t < 64) bdsh[t] = bd[t];

    // ---- bilinear params once per (tap,pixel)
    const float* goff = dout + OUT_OFF_BASE + (size_t)b * 1458;
    const float* gmsk = maskbuf + (size_t)b * 729;
    for (int i = t; i < 729; i += 256) {
        int k = i / 81, p = i - k * 81;
        float dy = goff[(2 * k) * 81 + p];
        float dx = goff[(2 * k + 1) * 81 + p];
        float m  = gmsk[i];
        int y = p / 9, xx = p - y * 9;
        float py = dy + (float)(y + k / 3 - 1);
        float px = dx + (float)(xx + (k % 3) - 1);
        float fy = floorf(py), fx = floorf(px);
        float ly = py - fy, lx = px - fx;
        int y0 = (int)fy, x0 = (int)fx;
        int y1 = y0 + 1, x1 = x0 + 1;
        bool vy0 = (y0 >= 0) & (y0 < 9), vy1 = (y1 >= 0) & (y1 < 9);
        bool vx0 = (x0 >= 0) & (x0 < 9), vx1 = (x1 >= 0) & (x1 < 9);
        float w00 = (vy0 && vx0) ? m * (1.f - ly) * (1.f - lx) : 0.f;
        float w01 = (vy0 && vx1) ? m * (1.f - ly) * lx : 0.f;
        float w10 = (vy1 && vx0) ? m * ly * (1.f - lx) : 0.f;
        float w11 = (vy1 && vx1) ? m * ly * lx : 0.f;
        int yc0 = min(max(y0, 0), 8), yc1 = min(max(y1, 0), 8);
        int xc0 = min(max(x0, 0), 8), xc1 = min(max(x1, 0), 8);
        unsigned i00 = yc0 * 9 + xc0, i01 = yc0 * 9 + xc1;
        unsigned i10 = yc1 * 9 + xc0, i11 = yc1 * 9 + xc1;
        bwt[i] = make_uint2((unsigned)f2bf(w00) | ((unsigned)f2bf(w01) << 16),
                            (unsigned)f2bf(w10) | ((unsigned)f2bf(w11) << 16));
        bix[i] = i00 | (i01 << 8) | (i10 << 16) | (i11 << 24);
    }
    __syncthreads();

    // ---- helpers for staging tap kk into buffer nb
    auto stage_tap = [&](int kk, int nb) {
        // W_k: 64x64 bf16 -> wk[nb][o*VSTR + c]
        for (int q = t; q < 512; q += 256) {
            int o = q >> 3, cs = (q & 7) * 8;
            *(uint4*)&wk[nb][o * VSTR + cs] =
                *(const uint4*)&wdt16[(kk * 64 + o) * 64 + cs];
        }
        // V_k: compute 2 channels per thread, c-major for conflict-free access
        int kbase = kk * 81;
        for (int i = t; i < 2592; i += 256) {
            int c2 = i & 31, p = i >> 5;
            uint2 bw = bwt[kbase + p];
            unsigned ix = bix[kbase + p];
            float w00 = bfhi2f(bw.x << 16), w01 = bfhi2f(bw.x & 0xffff0000u);
            float w10 = bfhi2f(bw.y << 16), w11 = bfhi2f(bw.y & 0xffff0000u);
            int i00 = ix & 255, i01 = (ix >> 8) & 255, i10 = (ix >> 16) & 255, i11 = ix >> 24;
            const float* h0 = &hsh[(2 * c2) * 81];
            const float* h1r = h0 + 81;
            float s0 = w00 * h0[i00] + w01 * h0[i01] + w10 * h0[i10] + w11 * h0[i11];
            float s1 = w00 * h1r[i00] + w01 * h1r[i01] + w10 * h1r[i10] + w11 * h1r[i11];
            *(unsigned*)&vt[nb][p * VSTR + 2 * c2] =
                (unsigned)f2bf(s0) | ((unsigned)f2bf(s1) << 16);
        }
    };

    stage_tap(0, 0);
    __syncthreads();

    int lane = t & 63, wv = t >> 6;
    int lg = lane >> 4, lr = lane & 15;
    floatx4 acc[6];
#pragma unroll
    for (int n = 0; n < 6; ++n) acc[n] = (floatx4)0.f;

    for (int k = 0; k < 9; ++k) {
        int cur = k & 1;
        if (k < 8) stage_tap(k + 1, cur ^ 1);
        const short* wbp = &wk[cur][(wv * 16 + lr) * VSTR + 8 * lg];
        bfrag8 a0 = *(const bfrag8*)wbp;
        bfrag8 a1 = *(const bfrag8*)(wbp + 32);
#pragma unroll
        for (int n = 0; n < 6; ++n) {
            const short* vbp = &vt[cur][(n * 16 + lr) * VSTR + 8 * lg];
            bfrag8 b0 = *(const bfrag8*)vbp;
            bfrag8 b1 = *(const bfrag8*)(vbp + 32);
            acc[n] = __builtin_amdgcn_mfma_f32_16x16x32_bf16(a0, b0, acc[n], 0, 0, 0);
            acc[n] = __builtin_amdgcn_mfma_f32_16x16x32_bf16(a1, b1, acc[n], 0, 0, 0);
        }
        __syncthreads();
    }

    // ---- epilogue: bias, write pre-BN output, BN2 stats
    float* outb = dout + OUT_H_BASE + (size_t)b * 5184;
    int obase = wv * 16 + 4 * lg;
#pragma unroll
    for (int j = 0; j < 4; ++j) {
        int o = obase + j;
        float bias = bdsh[o];
        float ss = 0.f, qq = 0.f;
#pragma unroll
        for (int n = 0; n < 6; ++n) {
            int p = n * 16 + lr;
            float v = acc[n][j] + bias;
            if (p < 81) { outb[o * 81 + p] = v; ss += v; qq += v * v; }
        }
#pragma unroll
        for (int off = 1; off < 16; off <<= 1) {
            ss += __shfl_xor(ss, off);
            qq += __shfl_xor(qq, off);
        }
        if (lr == 0) { atomicAdd(&sum2[o], ss); atomicAdd(&sq2[o], qq); }
    }
}

// ---------------- launch -------------------------------------------------------
extern "C" void kernel_launch(void* const* d_in, const int* in_sizes, int n_in,
                              void* d_out, int out_size, void* d_ws, size_t ws_size,
                              hipStream_t stream) {
    const float* x   = (const float*)d_in[0];
    const float* w1  = (const float*)d_in[1];
    const float* b1  = (const float*)d_in[2];
    const float* g1  = (const float*)d_in[3];
    const float* be1 = (const float*)d_in[4];
    const float* wo  = (const float*)d_in[5];
    const float* bo  = (const float*)d_in[6];
    const float* wm  = (const float*)d_in[7];
    const float* bm  = (const float*)d_in[8];
    const float* wd  = (const float*)d_in[9];
    const float* bd  = (const float*)d_in[10];
    const float* g2  = (const float*)d_in[11];
    const float* be2 = (const float*)d_in[12];
    float* dout = (float*)d_out;
    float* ws   = (float*)d_ws;

    float* h1    = ws + WS_H1;
    float* maskb = ws + WS_MASK;
    float* w1t   = ws + WS_W1T;
    float* wct   = ws + WS_WCT;
    const unsigned short* wdt16 = (const unsigned short*)(ws + WS_WDT);
    float* stats = ws + WS_STATS;
    float* sum1 = stats, *sq1 = stats + 64, *sum2 = stats + 128, *sq2 = stats + 192;
    float* scale1 = stats + 256, *shift1 = stats + 320, *scale2 = stats + 384, *shift2 = stats + 448;

    // zero the BN accumulators (ws is NOT re-poisoned between replays)
    hipMemsetAsync(stats, 0, 256 * sizeof(float), stream);

    prep_weights<<<306, 256, 0, stream>>>(w1, wo, wm, wd, ws);
    conv1_bn_stats<<<BATCH, 256, 0, stream>>>(x, b1, w1t, h1, sum1, sq1);
    bn_finalize<<<1, 64, 0, stream>>>(sum1, sq1, g1, be1, scale1, shift1);
    bn_apply<<<2048, 256, 0, stream>>>(h1, scale1, shift1, BATCH * 5184, 0, dout);
    conv_offmask<<<BATCH, 256, 0, stream>>>(h1, wct, bo, bm, dout, maskb);
    deform_mfma<<<BATCH, 256, 0, stream>>>(h1, wdt16, maskb, bd, dout, sum2, sq2);
    bn_finalize<<<1, 64, 0, stream>>>(sum2, sq2, g2, be2, scale2, shift2);
    bn_apply<<<2048, 256, 0, stream>>>(dout + OUT_H_BASE, scale2, shift2, BATCH * 5184, 1, dout);
}

// Round 3
// 528.922 us; speedup vs baseline: 2.5104x; 1.8591x over previous
//
#include <hip/hip_runtime.h>
#include <hip/hip_bf16.h>

// Problem constants
#define BATCH   2048
#define HW      81          // 9x9
#define CIN     39
#define NPIX    (BATCH*HW)  // 165888

// ws layout (float offsets)
#define WS_H1     0              // 10,616,832 floats  (B,64,81)  PRE-BN h
#define WS_MASK   10616832       // 1,492,992 floats   (B,9,81)
#define WS_WDT    12109824       // 36,864 ushort bf16 [k][o][c]   (18,432 floats)
#define WS_W1M    12128256       // 24,576 ushort bf16 [12][64][32] (12,288 floats)
#define WS_WCM    12140544       // 18,432 ushort bf16 [18][32][32] (9,216 floats)
#define WS_STATS  12149760       // 512 floats: sum1,sq1,sum2,sq2,scale1,shift1,scale2,shift2

#define OUT_OFF_BASE 1
#define OUT_H_BASE   (1 + BATCH*18*81)   // 2985985

typedef __attribute__((ext_vector_type(8))) short bfrag8;
typedef __attribute__((ext_vector_type(4))) float floatx4;

__device__ __forceinline__ unsigned short f2bf(float f) {
    unsigned u = __builtin_bit_cast(unsigned, f);
    u += 0x7FFFu + ((u >> 16) & 1u);       // round-to-nearest-even
    return (unsigned short)(u >> 16);
}
__device__ __forceinline__ float bfhi2f(unsigned hi16) {   // hi16 already in bits 31..16
    return __builtin_bit_cast(float, hi16);
}

// ---------------- weight prep: fragment-ready bf16 layouts --------------------
// w1m: [s(12)][o(64)][kk(32)]  k-map: s<9: (tap=s, c=kk); s=9: (tap=kk>>3, c=32+(kk&7));
//      s=10: (tap=4+(kk>>3), c=32+(kk&7)); s=11: (tap=8, c=32+(kk&7)) for kk<8 else 0.
// wcm: [s(18)][oc(32)][kk(32)] k-map: tap=s>>1, c=(s&1)*32+kk. oc>=27 rows zero.
// wdt: [k(9)][o(64)][c(64)] bf16 (deform)
__global__ void prep_weights(const float* __restrict__ w1, const float* __restrict__ wo,
                             const float* __restrict__ wm, const float* __restrict__ wd,
                             float* __restrict__ ws) {
    int idx = blockIdx.x * 256 + threadIdx.x;
    unsigned short* w1m = (unsigned short*)(ws + WS_W1M);
    unsigned short* wcm = (unsigned short*)(ws + WS_WCM);
    unsigned short* wdt16 = (unsigned short*)(ws + WS_WDT);
    if (idx < 24576) {
        int kk = idx & 31, o = (idx >> 5) & 63, s = idx >> 11;
        int tap, c; bool ok = true;
        if (s < 9)       { tap = s;             c = kk; }
        else if (s == 9) { tap = kk >> 3;       c = 32 + (kk & 7); }
        else if (s == 10){ tap = 4 + (kk >> 3); c = 32 + (kk & 7); }
        else             { tap = 8;             c = 32 + (kk & 7); ok = (kk < 8); }
        float v = (ok && c < CIN) ? w1[(o * CIN + c) * 9 + tap] : 0.f;
        w1m[idx] = f2bf(v);
        return;
    }
    int j = idx - 24576;
    if (j >= 0 && j < 18432) {
        int kk = j & 31, oc = (j >> 5) & 31, s = j >> 10;
        int tap = s >> 1, c = (s & 1) * 32 + kk;
        float v = 0.f;
        if (oc < 18)      v = wo[(oc * 64 + c) * 9 + tap];
        else if (oc < 27) v = wm[((oc - 18) * 64 + c) * 9 + tap];
        wcm[j] = f2bf(v);
        return;
    }
    int m = idx - 24576 - 18432;
    if (m >= 0 && m < 36864) {
        int c = m & 63, o = (m >> 6) & 63, k = m >> 12;
        wdt16[m] = f2bf(wd[(o * 64 + c) * 9 + k]);
    }
}

// ---------------- conv1 (39->64) MFMA + ReLU + BN1 stats ----------------------
// out[64 o][81 p] = W1[o][tap,c] * X[tap,c][p]; padded swizzled bf16 image in LDS.
__global__ __launch_bounds__(256) void conv1_mfma(
        const float* __restrict__ xg, const float* __restrict__ b1,
        const unsigned short* __restrict__ w1m, float* __restrict__ h1,
        float* __restrict__ sum1, float* __restrict__ sq1) {
    __shared__ short xs[128 * 64];   // [r(121)][c(64)] bf16, byte ^= (r&7)<<4
    int b = blockIdx.x, t = threadIdx.x;
    for (int i = t; i < 4096; i += 256) ((unsigned*)xs)[i] = 0u;
    __syncthreads();
    const float* xb = xg + (size_t)b * (HW * CIN);
    for (int i = t; i < HW * CIN; i += 256) {
        int p = i / 39, c = i - 39 * p;
        int y = p / 9, xx = p - 9 * y;
        int r = (y + 1) * 11 + xx + 1;
        int byte = r * 128 + ((c * 2) ^ ((r & 7) << 4));
        xs[byte >> 1] = (short)f2bf(xb[i]);
    }
    __syncthreads();
    int lane = t & 63, wv = t >> 6, lg = lane >> 4, lr = lane & 15;
    int o = wv * 16 + lr;
    bfrag8 a[12];
#pragma unroll
    for (int s = 0; s < 12; ++s)
        a[s] = *(const bfrag8*)&w1m[(s * 64 + o) * 32 + lg * 8];
    floatx4 acc[6];
#pragma unroll
    for (int n = 0; n < 6; ++n) acc[n] = (floatx4)0.f;
#pragma unroll
    for (int n = 0; n < 6; ++n) {
        int p = n * 16 + lr; p = p > 80 ? 80 : p;
        int y = p / 9, xx = p - 9 * y;
        int rb = (y + 1) * 11 + xx + 1;
#pragma unroll
        for (int s = 0; s < 12; ++s) {
            int r, cb;
            if (s < 9)       { r = rb + (s / 3 - 1) * 11 + (s % 3) - 1; cb = lg * 16; }
            else if (s == 9) { r = rb + (lg / 3 - 1) * 11 + (lg % 3) - 1; cb = 64; }
            else if (s == 10){ int tp = lg + 4; r = rb + (tp / 3 - 1) * 11 + (tp % 3) - 1; cb = 64; }
            else             { r = rb + 12; cb = 64; }
            int byte = r * 128 + (cb ^ ((r & 7) << 4));
            bfrag8 bf = *(const bfrag8*)((const char*)xs + byte);
            acc[n] = __builtin_amdgcn_mfma_f32_16x16x32_bf16(a[s], bf, acc[n], 0, 0, 0);
        }
    }
    float* h1b = h1 + (size_t)b * 5184;
#pragma unroll
    for (int j = 0; j < 4; ++j) {
        int oo = wv * 16 + lg * 4 + j;
        float bias = b1[oo];
        float ss = 0.f, qq = 0.f;
#pragma unroll
        for (int n = 0; n < 6; ++n) {
            int p = n * 16 + lr;
            float v = fmaxf(acc[n][j] + bias, 0.f);
            if (p < 81) { h1b[oo * 81 + p] = v; ss += v; qq += v * v; }
        }
#pragma unroll
        for (int off = 1; off < 16; off <<= 1) { ss += __shfl_xor(ss, off); qq += __shfl_xor(qq, off); }
        if (lr == 0) { atomicAdd(&sum1[oo], ss); atomicAdd(&sq1[oo], qq); }
    }
}

// ---------------- BN finalize -------------------------------------------------
__global__ void bn_finalize(const float* __restrict__ sums, const float* __restrict__ sqs,
                            const float* __restrict__ gamma, const float* __restrict__ beta,
                            float* __restrict__ scale, float* __restrict__ shift) {
    int t = threadIdx.x;   // 64
    float m = sums[t] / (float)NPIX;
    float v = sqs[t] / (float)NPIX - m * m;
    float sc = gamma[t] * (1.f / sqrtf(v + 1e-5f));
    scale[t] = sc;
    shift[t] = beta[t] - m * sc;
}

// ---------------- BN apply (final output) -------------------------------------
__global__ void bn_apply(float* __restrict__ data, const float* __restrict__ scale,
                         const float* __restrict__ shift, int n, int writeProb,
                         float* __restrict__ dout) {
    int i = blockIdx.x * blockDim.x + threadIdx.x;
    if (writeProb && i == 0) dout[0] = 0.5f;
    for (; i < n; i += gridDim.x * blockDim.x) {
        int c = (i / 81) & 63;
        data[i] = data[i] * scale[c] + shift[c];
    }
}

// ---------------- offset(18) + mask(9, sigmoid) conv, MFMA --------------------
// BN1 folded in at staging (h1 is pre-BN).
__global__ __launch_bounds__(256) void offmask_mfma(
        const float* __restrict__ h1, const unsigned short* __restrict__ wcm,
        const float* __restrict__ bo, const float* __restrict__ bm,
        const float* __restrict__ scale1, const float* __restrict__ shift1,
        float* __restrict__ dout, float* __restrict__ maskbuf) {
    __shared__ float hsh[5184];
    __shared__ short xs[128 * 64];   // padded swizzled bf16 post-BN image
    __shared__ float sc[64], sh[64];
    int b = blockIdx.x, t = threadIdx.x;
    for (int i = t; i < 4096; i += 256) ((unsigned*)xs)[i] = 0u;
    if (t < 128) { if (t < 64) sc[t] = scale1[t]; else sh[t - 64] = shift1[t - 64]; }
    const float* hb = h1 + (size_t)b * 5184;
    for (int i = t; i < 1296; i += 256) ((float4*)hsh)[i] = ((const float4*)hb)[i];
    __syncthreads();
    for (int i = t; i < 5184; i += 256) {
        int p = i >> 6, c = i & 63;                  // lanes: same p, consecutive c
        float v = hsh[c * 81 + p] * sc[c] + sh[c];   // stride-81 read: 2-way, free
        int y = p / 9, xx = p - 9 * y;
        int r = (y + 1) * 11 + xx + 1;
        int byte = r * 128 + ((c * 2) ^ ((r & 7) << 4));
        xs[byte >> 1] = (short)f2bf(v);
    }
    __syncthreads();
    int lane = t & 63, wv = t >> 6, lg = lane >> 4, lr = lane & 15;
    int mt = wv >> 1, nh = (wv & 1) * 3;
    int ocr = mt * 16 + lr;
    bfrag8 a[18];
#pragma unroll
    for (int s = 0; s < 18; ++s)
        a[s] = *(const bfrag8*)&wcm[(s * 32 + ocr) * 32 + lg * 8];
    floatx4 acc[3];
#pragma unroll
    for (int n = 0; n < 3; ++n) acc[n] = (floatx4)0.f;
#pragma unroll
    for (int ni = 0; ni < 3; ++ni) {
        int p = (nh + ni) * 16 + lr; p = p > 80 ? 80 : p;
        int y = p / 9, xx = p - 9 * y;
        int rb = (y + 1) * 11 + xx + 1;
#pragma unroll
        for (int s = 0; s < 18; ++s) {
            int tap = s >> 1, ch = s & 1;
            int r = rb + (tap / 3 - 1) * 11 + (tap % 3) - 1;
            int byte = r * 128 + ((ch * 64 + lg * 16) ^ ((r & 7) << 4));
            bfrag8 bf = *(const bfrag8*)((const char*)xs + byte);
            acc[ni] = __builtin_amdgcn_mfma_f32_16x16x32_bf16(a[s], bf, acc[ni], 0, 0, 0);
        }
    }
#pragma unroll
    for (int j = 0; j < 4; ++j) {
        int oc = mt * 16 + lg * 4 + j;
        if (oc < 18) {
            float bias = bo[oc];
            float* ob = dout + OUT_OFF_BASE + (size_t)b * 1458 + oc * 81;
#pragma unroll
            for (int ni = 0; ni < 3; ++ni) {
                int p = (nh + ni) * 16 + lr;
                if (p < 81) ob[p] = acc[ni][j] + bias;
            }
        } else if (oc < 27) {
            float bias = bm[oc - 18];
            float* mb = maskbuf + (size_t)b * 729 + (oc - 18) * 81;
#pragma unroll
            for (int ni = 0; ni < 3; ++ni) {
                int p = (nh + ni) * 16 + lr;
                if (p < 81) { float v = acc[ni][j] + bias; mb[p] = 1.f / (1.f + expf(-v)); }
            }
        }
    }
}

// ---------------- deformable conv (MFMA) + BN2 stats --------------------------
// BN1 folded in at staging (h1 is pre-BN).
#define VSTR 72
__global__ __launch_bounds__(256) void deform_mfma(
        const float* __restrict__ h1, const unsigned short* __restrict__ wdt16,
        const float* __restrict__ maskbuf, const float* __restrict__ bd,
        const float* __restrict__ scale1, const float* __restrict__ shift1,
        float* __restrict__ dout, float* __restrict__ sum2, float* __restrict__ sq2) {
    __shared__ float hsh[5184];                 // [c][81] fp32 post-BN
    __shared__ uint2 bwt[729];                  // [k][p] 4x bf16 weights (pre-masked)
    __shared__ unsigned bix[729];               // [k][p] 4x u8 corner indices
    __shared__ short wk[2][64 * VSTR];          // [o][c] bf16, double buffered
    __shared__ short vt[2][96 * VSTR];          // [p][c] bf16, double buffered
    __shared__ float bdsh[64], scs[64], shs[64];

    int b = blockIdx.x, t = threadIdx.x;
    if (t < 64) { bdsh[t] = bd[t]; scs[t] = scale1[t]; shs[t] = shift1[t]; }
    __syncthreads();

    // ---- stage h (fp32, BN applied)
    const float* hb = h1 + (size_t)b * 5184;
    for (int i = t; i < 5184; i += 256) {
        int c = i / 81;
        hsh[i] = hb[i] * scs[c] + shs[c];
    }

    // ---- bilinear params once per (tap,pixel)
    const float* goff = dout + OUT_OFF_BASE + (size_t)b * 1458;
    const float* gmsk = maskbuf + (size_t)b * 729;
    for (int i = t; i < 729; i += 256) {
        int k = i / 81, p = i - k * 81;
        float dy = goff[(2 * k) * 81 + p];
        float dx = goff[(2 * k + 1) * 81 + p];
        float m  = gmsk[i];
        int y = p / 9, xx = p - y * 9;
        float py = dy + (float)(y + k / 3 - 1);
        float px = dx + (float)(xx + (k % 3) - 1);
        float fy = floorf(py), fx = floorf(px);
        float ly = py - fy, lx = px - fx;
        int y0 = (int)fy, x0 = (int)fx;
        int y1 = y0 + 1, x1 = x0 + 1;
        bool vy0 = (y0 >= 0) & (y0 < 9), vy1 = (y1 >= 0) & (y1 < 9);
        bool vx0 = (x0 >= 0) & (x0 < 9), vx1 = (x1 >= 0) & (x1 < 9);
        float w00 = (vy0 && vx0) ? m * (1.f - ly) * (1.f - lx) : 0.f;
        float w01 = (vy0 && vx1) ? m * (1.f - ly) * lx : 0.f;
        float w10 = (vy1 && vx0) ? m * ly * (1.f - lx) : 0.f;
        float w11 = (vy1 && vx1) ? m * ly * lx : 0.f;
        int yc0 = min(max(y0, 0), 8), yc1 = min(max(y1, 0), 8);
        int xc0 = min(max(x0, 0), 8), xc1 = min(max(x1, 0), 8);
        unsigned i00 = yc0 * 9 + xc0, i01 = yc0 * 9 + xc1;
        unsigned i10 = yc1 * 9 + xc0, i11 = yc1 * 9 + xc1;
        bwt[i] = make_uint2((unsigned)f2bf(w00) | ((unsigned)f2bf(w01) << 16),
                            (unsigned)f2bf(w10) | ((unsigned)f2bf(w11) << 16));
        bix[i] = i00 | (i01 << 8) | (i10 << 16) | (i11 << 24);
    }
    __syncthreads();

    auto stage_tap = [&](int kk, int nb) {
        for (int q = t; q < 512; q += 256) {
            int o = q >> 3, cs = (q & 7) * 8;
            *(uint4*)&wk[nb][o * VSTR + cs] =
                *(const uint4*)&wdt16[(kk * 64 + o) * 64 + cs];
        }
        int kbase = kk * 81;
        for (int i = t; i < 2592; i += 256) {
            int c2 = i & 31, p = i >> 5;
            uint2 bw = bwt[kbase + p];
            unsigned ix = bix[kbase + p];
            float w00 = bfhi2f(bw.x << 16), w01 = bfhi2f(bw.x & 0xffff0000u);
            float w10 = bfhi2f(bw.y << 16), w11 = bfhi2f(bw.y & 0xffff0000u);
            int i00 = ix & 255, i01 = (ix >> 8) & 255, i10 = (ix >> 16) & 255, i11 = ix >> 24;
            const float* h0 = &hsh[(2 * c2) * 81];
            const float* h1r = h0 + 81;
            float s0 = w00 * h0[i00] + w01 * h0[i01] + w10 * h0[i10] + w11 * h0[i11];
            float s1 = w00 * h1r[i00] + w01 * h1r[i01] + w10 * h1r[i10] + w11 * h1r[i11];
            *(unsigned*)&vt[nb][p * VSTR + 2 * c2] =
                (unsigned)f2bf(s0) | ((unsigned)f2bf(s1) << 16);
        }
    };

    stage_tap(0, 0);
    __syncthreads();

    int lane = t & 63, wv = t >> 6;
    int lg = lane >> 4, lr = lane & 15;
    floatx4 acc[6];
#pragma unroll
    for (int n = 0; n < 6; ++n) acc[n] = (floatx4)0.f;

    for (int k = 0; k < 9; ++k) {
        int cur = k & 1;
        if (k < 8) stage_tap(k + 1, cur ^ 1);
        const short* wbp = &wk[cur][(wv * 16 + lr) * VSTR + 8 * lg];
        bfrag8 a0 = *(const bfrag8*)wbp;
        bfrag8 a1 = *(const bfrag8*)(wbp + 32);
#pragma unroll
        for (int n = 0; n < 6; ++n) {
            const short* vbp = &vt[cur][(n * 16 + lr) * VSTR + 8 * lg];
            bfrag8 b0 = *(const bfrag8*)vbp;
            bfrag8 b1 = *(const bfrag8*)(vbp + 32);
            acc[n] = __builtin_amdgcn_mfma_f32_16x16x32_bf16(a0, b0, acc[n], 0, 0, 0);
            acc[n] = __builtin_amdgcn_mfma_f32_16x16x32_bf16(a1, b1, acc[n], 0, 0, 0);
        }
        __syncthreads();
    }

    float* outb = dout + OUT_H_BASE + (size_t)b * 5184;
    int obase = wv * 16 + 4 * lg;
#pragma unroll
    for (int j = 0; j < 4; ++j) {
        int o = obase + j;
        float bias = bdsh[o];
        float ss = 0.f, qq = 0.f;
#pragma unroll
        for (int n = 0; n < 6; ++n) {
            int p = n * 16 + lr;
            float v = acc[n][j] + bias;
            if (p < 81) { outb[o * 81 + p] = v; ss += v; qq += v * v; }
        }
#pragma unroll
        for (int off = 1; off < 16; off <<= 1) {
            ss += __shfl_xor(ss, off);
            qq += __shfl_xor(qq, off);
        }
        if (lr == 0) { atomicAdd(&sum2[o], ss); atomicAdd(&sq2[o], qq); }
    }
}

// ---------------- launch -------------------------------------------------------
extern "C" void kernel_launch(void* const* d_in, const int* in_sizes, int n_in,
                              void* d_out, int out_size, void* d_ws, size_t ws_size,
                              hipStream_t stream) {
    const float* x   = (const float*)d_in[0];
    const float* w1  = (const float*)d_in[1];
    const float* b1  = (const float*)d_in[2];
    const float* g1  = (const float*)d_in[3];
    const float* be1 = (const float*)d_in[4];
    const float* wo  = (const float*)d_in[5];
    const float* bo  = (const float*)d_in[6];
    const float* wm  = (const float*)d_in[7];
    const float* bm  = (const float*)d_in[8];
    const float* wd  = (const float*)d_in[9];
    const float* bd  = (const float*)d_in[10];
    const float* g2  = (const float*)d_in[11];
    const float* be2 = (const float*)d_in[12];
    float* dout = (float*)d_out;
    float* ws   = (float*)d_ws;

    float* h1    = ws + WS_H1;
    float* maskb = ws + WS_MASK;
    const unsigned short* wdt16 = (const unsigned short*)(ws + WS_WDT);
    const unsigned short* w1m   = (const unsigned short*)(ws + WS_W1M);
    const unsigned short* wcm   = (const unsigned short*)(ws + WS_WCM);
    float* stats = ws + WS_STATS;
    float* sum1 = stats, *sq1 = stats + 64, *sum2 = stats + 128, *sq2 = stats + 192;
    float* scale1 = stats + 256, *shift1 = stats + 320, *scale2 = stats + 384, *shift2 = stats + 448;

    // zero the BN accumulators (ws is NOT re-poisoned between replays)
    hipMemsetAsync(stats, 0, 256 * sizeof(float), stream);

    prep_weights<<<312, 256, 0, stream>>>(w1, wo, wm, wd, ws);
    conv1_mfma<<<BATCH, 256, 0, stream>>>(x, b1, w1m, h1, sum1, sq1);
    bn_finalize<<<1, 64, 0, stream>>>(sum1, sq1, g1, be1, scale1, shift1);
    offmask_mfma<<<BATCH, 256, 0, stream>>>(h1, wcm, bo, bm, scale1, shift1, dout, maskb);
    deform_mfma<<<BATCH, 256, 0, stream>>>(h1, wdt16, maskb, bd, scale1, shift1, dout, sum2, sq2);
    bn_finalize<<<1, 64, 0, stream>>>(sum2, sq2, g2, be2, scale2, shift2);
    bn_apply<<<2048, 256, 0, stream>>>(dout + OUT_H_BASE, scale2, shift2, BATCH * 5184, 1, dout);
}